// Round 6
// baseline (732.805 us; speedup 1.0000x reference)
//
#include <hip/hip_runtime.h>
#include <math.h>

#define N_NODES 100000
#define N_EDGES 1600000
#define IN_DIM 128
#define HID_DIM 64
#define OUT_DIM 40

#define NPAD 102400
#define SCAN_CHUNK 1024
#define NB ((N_NODES + SCAN_CHUNK - 1) / SCAN_CHUNK)  // 98 blocks

#define BUCKET_SHIFT 7
#define BUCKET_NODES 128
#define N_BUCKETS ((N_NODES + BUCKET_NODES - 1) / BUCKET_NODES)  // 782

typedef _Float16 f16;
typedef _Float16 f16x2 __attribute__((ext_vector_type(2)));
typedef _Float16 f16x4 __attribute__((ext_vector_type(4)));

// -------- workspace layout (int region first, then fp regions) --------
// ints:  cnt[NPAD] | row_start[NPAD] | blockSums[128] | bcur[1024] | csr[E] | stage[E]
// floats: dinv[NPAD] | z[N*64]
// f16:    h1p[N*64] | h2p[N*40]
// zeroed per launch: cnt (NPAD ints = 0.4 MB)

__global__ void count_kernel(const int* __restrict__ dst, int* __restrict__ cnt) {
    int e = blockIdx.x * blockDim.x + threadIdx.x;
    if (e < N_EDGES) atomicAdd(&cnt[dst[e]], 1);
}

__global__ void dinv_kernel(const int* __restrict__ cnt, float* __restrict__ dinv) {
    int i = blockIdx.x * blockDim.x + threadIdx.x;
    if (i < N_NODES) dinv[i] = rsqrtf((float)cnt[i] + 1.0f);
}

// exclusive scan, stage 1: per-block (1024 elements, 256 thr x 4) partial scan
__global__ __launch_bounds__(256) void scan_partial_kernel(const int* __restrict__ cnt,
                                                           int* __restrict__ excl,
                                                           int* __restrict__ blockSums) {
    __shared__ int lds[256];
    int base = blockIdx.x * SCAN_CHUNK;
    int t = threadIdx.x;
    int v[4];
    int s = 0;
    for (int k = 0; k < 4; ++k) {
        int idx = base + t * 4 + k;
        int c = (idx < N_NODES) ? cnt[idx] : 0;
        v[k] = s;
        s += c;
    }
    lds[t] = s;
    __syncthreads();
    for (int off = 1; off < 256; off <<= 1) {
        int val = (t >= off) ? lds[t - off] : 0;
        __syncthreads();
        lds[t] += val;
        __syncthreads();
    }
    int thread_excl = (t == 0) ? 0 : lds[t - 1];
    if (t == 255) blockSums[blockIdx.x] = lds[255];
    for (int k = 0; k < 4; ++k) {
        int idx = base + t * 4 + k;
        if (idx < N_NODES) excl[idx] = thread_excl + v[k];
    }
}

__global__ __launch_bounds__(128) void scan_blocksums_kernel(int* __restrict__ blockSums) {
    __shared__ int lds[128];
    int t = threadIdx.x;
    int v = (t < NB) ? blockSums[t] : 0;
    lds[t] = v;
    __syncthreads();
    for (int off = 1; off < 128; off <<= 1) {
        int val = (t >= off) ? lds[t - off] : 0;
        __syncthreads();
        lds[t] += val;
        __syncthreads();
    }
    int excl = (t == 0) ? 0 : lds[t - 1];
    if (t < NB) blockSums[t] = excl;
}

__global__ void scan_add_kernel(int* __restrict__ excl, const int* __restrict__ blockSums) {
    int idx = blockIdx.x * blockDim.x + threadIdx.x;
    if (idx < N_NODES) excl[idx] += blockSums[idx / SCAN_CHUNK];
}

__global__ void bcur_init_kernel(const int* __restrict__ row_start, int* __restrict__ bcur) {
    int b = blockIdx.x * blockDim.x + threadIdx.x;
    if (b < N_BUCKETS) bcur[b] = row_start[b << BUCKET_SHIFT];
}

// Pass 1: append each edge's packed record to its dst-bucket's region of stage.
// Bucket regions coincide with csr node-range regions (exact capacity by construction);
// append-order allocation makes stage writes line-dense -> full-line writebacks.
__global__ void bucket_scatter_kernel(const int* __restrict__ src, const int* __restrict__ dst,
                                      int* __restrict__ bcur, int* __restrict__ stage) {
    int e = blockIdx.x * blockDim.x + threadIdx.x;
    if (e < N_EDGES) {
        int d = dst[e];
        int b = d >> BUCKET_SHIFT;
        int pos = atomicAdd(&bcur[b], 1);
        stage[pos] = ((d & (BUCKET_NODES - 1)) << 17) | src[e];
    }
}

// Pass 2: one block per bucket; LDS cursors; csr writes confined to the bucket's
// contiguous ~8KB window -> L2-resident, full-line writebacks.
__global__ __launch_bounds__(256) void bucket_place_kernel(const int* __restrict__ stage,
                                                           const int* __restrict__ row_start,
                                                           int* __restrict__ csr) {
    __shared__ int lcur[BUCKET_NODES];
    int b = blockIdx.x;
    int nodeBase = b << BUCKET_SHIFT;
    int t = threadIdx.x;
    if (t < BUCKET_NODES) lcur[t] = 0;
    __syncthreads();
    int estart = row_start[nodeBase];
    int eend = (b == N_BUCKETS - 1) ? N_EDGES : row_start[nodeBase + BUCKET_NODES];
    for (int e = estart + t; e < eend; e += 256) {
        int rec = stage[e];
        int dl = rec >> 17;
        int s = rec & 0x1FFFF;
        int pos = row_start[nodeBase + dl] + atomicAdd(&lcur[dl], 1);
        csr[pos] = s;
    }
}

// ---------------- gemm1: h1p[i][j] = f16( dinv[i] * sum_k x[i][k] * W1[k][j] ) ----------------
#define G1_XS 36
__global__ __launch_bounds__(256) void gemm1_kernel(const float* __restrict__ x,
                                                    const float* __restrict__ W1,
                                                    const float* __restrict__ dinv,
                                                    f16* __restrict__ h1p) {
    __shared__ float ws[IN_DIM * HID_DIM];   // 32 KB
    __shared__ float xT[IN_DIM * G1_XS];     // 18 KB
    int t = threadIdx.x;
    int nodeBase = blockIdx.x * 32;

    const float4* W4 = (const float4*)W1;
    float4* ws4 = (float4*)ws;
#pragma unroll
    for (int i = 0; i < 8; ++i) ws4[t + 256 * i] = W4[t + 256 * i];

    int kg = t & 31;
    int nd = t >> 5;
#pragma unroll
    for (int m = 0; m < 4; ++m) {
        int node = nd + 8 * m;
        const float* xr = x + (size_t)(nodeBase + node) * IN_DIM;
#pragma unroll
        for (int j = 0; j < 4; ++j) {
            xT[(kg + 32 * j) * G1_XS + node] = xr[kg + 32 * j];
        }
    }
    __syncthreads();

    int g = t >> 5;   // node group of 4
    int c = t & 31;   // col group of 2
    float a00 = 0.f, a01 = 0.f, a10 = 0.f, a11 = 0.f;
    float a20 = 0.f, a21 = 0.f, a30 = 0.f, a31 = 0.f;
#pragma unroll 4
    for (int k = 0; k < IN_DIM; ++k) {
        float4 xv = *(const float4*)&xT[k * G1_XS + 4 * g];
        float2 wv = *(const float2*)&ws[k * HID_DIM + 2 * c];
        a00 += xv.x * wv.x; a01 += xv.x * wv.y;
        a10 += xv.y * wv.x; a11 += xv.y * wv.y;
        a20 += xv.z * wv.x; a21 += xv.z * wv.y;
        a30 += xv.w * wv.x; a31 += xv.w * wv.y;
    }
    float r0[4] = {a00, a10, a20, a30};
    float r1[4] = {a01, a11, a21, a31};
#pragma unroll
    for (int i = 0; i < 4; ++i) {
        int n = nodeBase + 4 * g + i;
        float di = dinv[n];
        f16x2 o;
        o.x = (f16)(r0[i] * di);
        o.y = (f16)(r1[i] * di);
        *(f16x2*)&h1p[(size_t)n * HID_DIM + 2 * c] = o;
    }
}

// one wave per node: lanes = 64 hidden dims; gather-sum fp16 neighbor rows (fp32 acc)
__global__ __launch_bounds__(256) void agg1_kernel(const f16* __restrict__ h1p,
                                                   const int* __restrict__ csr,
                                                   const int* __restrict__ row_start,
                                                   const int* __restrict__ cnt,
                                                   const float* __restrict__ dinv,
                                                   const float* __restrict__ b1,
                                                   float* __restrict__ z) {
    int w = blockIdx.x * 4 + (threadIdx.x >> 6);
    int j = threadIdx.x & 63;
    if (w >= N_NODES) return;
    int s0 = row_start[w];
    int n  = cnt[w];
    const int* cp = csr + s0;
    float acc = (float)h1p[(size_t)w * HID_DIM + j];   // self loop
    int k = 0;
    for (; k + 4 <= n; k += 4) {
        int a = cp[k], b = cp[k + 1], c = cp[k + 2], d = cp[k + 3];
        float f0 = (float)h1p[(size_t)a * HID_DIM + j];
        float f1 = (float)h1p[(size_t)b * HID_DIM + j];
        float f2 = (float)h1p[(size_t)c * HID_DIM + j];
        float f3 = (float)h1p[(size_t)d * HID_DIM + j];
        acc += f0 + f1 + f2 + f3;
    }
    for (; k < n; ++k) acc += (float)h1p[(size_t)cp[k] * HID_DIM + j];
    float v = acc * dinv[w] + b1[j];
    z[(size_t)w * HID_DIM + j] = v > 0.f ? v : 0.f;
}

// ---------------- gemm2: h2p[i][j] = f16( dinv[i] * sum_k z[i][k] * W2[k][j] ) ----------------
#define G2_ZS 68
__global__ __launch_bounds__(256) void gemm2_kernel(const float* __restrict__ z,
                                                    const float* __restrict__ W2,
                                                    const float* __restrict__ dinv,
                                                    f16* __restrict__ h2p) {
    __shared__ float ws[HID_DIM * OUT_DIM];  // 2560 floats
    __shared__ float zT[HID_DIM * G2_ZS];    // 4352 floats
    int t = threadIdx.x;
    int nodeBase = blockIdx.x * 64;

    const float4* W4 = (const float4*)W2;
    float4* ws4 = (float4*)ws;
    for (int i = t; i < (HID_DIM * OUT_DIM) / 4; i += 256) ws4[i] = W4[i];

    int kg = t & 31;
    int nd = t >> 5;
#pragma unroll
    for (int m = 0; m < 8; ++m) {
        int node = nd + 8 * m;
        int n = nodeBase + node;
        float v0 = 0.f, v1 = 0.f;
        if (n < N_NODES) {
            const float* zr = z + (size_t)n * HID_DIM;
            v0 = zr[kg];
            v1 = zr[kg + 32];
        }
        zT[kg * G2_ZS + node] = v0;
        zT[(kg + 32) * G2_ZS + node] = v1;
    }
    __syncthreads();

    int g = t >> 4;   // node group of 4
    int c = t & 15;   // col group of 4; active c<10
    if (c < 10) {
        float acc[4][4] = {};
#pragma unroll 4
        for (int k = 0; k < HID_DIM; ++k) {
            float4 zv = *(const float4*)&zT[k * G2_ZS + 4 * g];
            float4 wv = *(const float4*)&ws[k * OUT_DIM + 4 * c];
            acc[0][0] += zv.x * wv.x; acc[0][1] += zv.x * wv.y; acc[0][2] += zv.x * wv.z; acc[0][3] += zv.x * wv.w;
            acc[1][0] += zv.y * wv.x; acc[1][1] += zv.y * wv.y; acc[1][2] += zv.y * wv.z; acc[1][3] += zv.y * wv.w;
            acc[2][0] += zv.z * wv.x; acc[2][1] += zv.z * wv.y; acc[2][2] += zv.z * wv.z; acc[2][3] += zv.z * wv.w;
            acc[3][0] += zv.w * wv.x; acc[3][1] += zv.w * wv.y; acc[3][2] += zv.w * wv.z; acc[3][3] += zv.w * wv.w;
        }
#pragma unroll
        for (int i = 0; i < 4; ++i) {
            int n = nodeBase + 4 * g + i;
            if (n < N_NODES) {
                float di = dinv[n];
                f16x4 o;
                o.x = (f16)(acc[i][0] * di);
                o.y = (f16)(acc[i][1] * di);
                o.z = (f16)(acc[i][2] * di);
                o.w = (f16)(acc[i][3] * di);
                *(f16x4*)&h2p[(size_t)n * OUT_DIM + 4 * c] = o;
            }
        }
    }
}

// one wave per node, lanes 0..39 = out dims; fp16 gather, fp32 acc
__global__ __launch_bounds__(256) void agg2_kernel(const f16* __restrict__ h2p,
                                                   const int* __restrict__ csr,
                                                   const int* __restrict__ row_start,
                                                   const int* __restrict__ cnt,
                                                   const float* __restrict__ dinv,
                                                   const float* __restrict__ b2,
                                                   float* __restrict__ out) {
    int w = blockIdx.x * 4 + (threadIdx.x >> 6);
    int j = threadIdx.x & 63;
    if (w >= N_NODES || j >= OUT_DIM) return;
    int s0 = row_start[w];
    int n  = cnt[w];
    const int* cp = csr + s0;
    float acc = (float)h2p[(size_t)w * OUT_DIM + j];   // self loop
    int k = 0;
    for (; k + 4 <= n; k += 4) {
        int a = cp[k], b = cp[k + 1], c = cp[k + 2], d = cp[k + 3];
        float f0 = (float)h2p[(size_t)a * OUT_DIM + j];
        float f1 = (float)h2p[(size_t)b * OUT_DIM + j];
        float f2 = (float)h2p[(size_t)c * OUT_DIM + j];
        float f3 = (float)h2p[(size_t)d * OUT_DIM + j];
        acc += f0 + f1 + f2 + f3;
    }
    for (; k < n; ++k) acc += (float)h2p[(size_t)cp[k] * OUT_DIM + j];
    out[(size_t)w * OUT_DIM + j] = acc * dinv[w] + b2[j];
}

extern "C" void kernel_launch(void* const* d_in, const int* in_sizes, int n_in,
                              void* d_out, int out_size, void* d_ws, size_t ws_size,
                              hipStream_t stream) {
    const float* x  = (const float*)d_in[0];
    const int*   ei = (const int*)d_in[1];      // [2, E] int32
    const float* W1 = (const float*)d_in[2];
    const float* b1 = (const float*)d_in[3];
    const float* W2 = (const float*)d_in[4];
    const float* b2 = (const float*)d_in[5];
    float* out = (float*)d_out;

    const int* src = ei;
    const int* dst = ei + N_EDGES;

    int* wsi       = (int*)d_ws;
    int* cnt       = wsi;
    int* row_start = wsi + NPAD;
    int* blockSums = wsi + 2 * NPAD;
    int* bcur      = wsi + 2 * NPAD + 128;
    int* csr       = wsi + 2 * NPAD + 128 + 1024;
    int* stage     = csr + N_EDGES;
    float* dinv    = (float*)(stage + N_EDGES);
    float* z       = dinv + NPAD;
    f16*   h1p     = (f16*)(z + (size_t)N_NODES * HID_DIM);
    f16*   h2p     = h1p + (size_t)N_NODES * HID_DIM;

    hipMemsetAsync(d_ws, 0, (size_t)NPAD * sizeof(int), stream);

    count_kernel<<<(N_EDGES + 255) / 256, 256, 0, stream>>>(dst, cnt);
    dinv_kernel<<<(N_NODES + 255) / 256, 256, 0, stream>>>(cnt, dinv);

    scan_partial_kernel<<<NB, 256, 0, stream>>>(cnt, row_start, blockSums);
    scan_blocksums_kernel<<<1, 128, 0, stream>>>(blockSums);
    scan_add_kernel<<<(N_NODES + 255) / 256, 256, 0, stream>>>(row_start, blockSums);
    bcur_init_kernel<<<(N_BUCKETS + 255) / 256, 256, 0, stream>>>(row_start, bcur);

    bucket_scatter_kernel<<<(N_EDGES + 255) / 256, 256, 0, stream>>>(src, dst, bcur, stage);
    bucket_place_kernel<<<N_BUCKETS, 256, 0, stream>>>(stage, row_start, csr);

    gemm1_kernel<<<N_NODES / 32, 256, 0, stream>>>(x, W1, dinv, h1p);

    agg1_kernel<<<(N_NODES + 3) / 4, 256, 0, stream>>>(h1p, csr, row_start, cnt, dinv, b1, z);

    gemm2_kernel<<<(N_NODES + 63) / 64, 256, 0, stream>>>(z, W2, dinv, h2p);

    agg2_kernel<<<(N_NODES + 3) / 4, 256, 0, stream>>>(h2p, csr, row_start, cnt, dinv, b2, out);
}

// Round 7
// 306.262 us; speedup vs baseline: 2.3927x; 2.3927x over previous
//
#include <hip/hip_runtime.h>
#include <math.h>

#define N_NODES 100000
#define N_EDGES 1600000
#define IN_DIM 128
#define HID_DIM 64
#define OUT_DIM 40

#define NPAD 102400

#define BUCKET_SHIFT 7
#define BUCKET_NODES 128
#define N_BUCKETS 782          // ceil(100000/128)
#define CHUNK 2048
#define N_CHUNKS 784           // 8 XCD groups x 98; 784*2048 >= N_EDGES

typedef _Float16 f16;
typedef _Float16 f16x2 __attribute__((ext_vector_type(2)));
typedef _Float16 f16x4 __attribute__((ext_vector_type(4)));

// -------- workspace layout --------
// ints:  hist[N_CHUNKS*N_BUCKETS] | base[N_BUCKETS*N_CHUNKS] | bucketTotal[1024] |
//        bucketBase[1024] | row_start[NPAD] | cnt[NPAD] | csr[E] | stage[E]
// floats: dinv[NPAD] | z[N*64]
// f16:    h1p[N*64] | h2p[N*40]
// NO memset needed: every buffer fully written before read each launch.

// 1) per-chunk LDS histogram over dst buckets; coalesced row write
__global__ __launch_bounds__(256) void hist_kernel(const int* __restrict__ dst,
                                                   int* __restrict__ hist) {
    __shared__ int lh[N_BUCKETS];
    int c = blockIdx.x;
    int t = threadIdx.x;
    for (int b = t; b < N_BUCKETS; b += 256) lh[b] = 0;
    __syncthreads();
    int e0 = c * CHUNK;
    for (int i = t; i < CHUNK; i += 256) {
        int e = e0 + i;
        if (e < N_EDGES) atomicAdd(&lh[dst[e] >> BUCKET_SHIFT], 1);
    }
    __syncthreads();
    for (int b = t; b < N_BUCKETS; b += 256) hist[c * N_BUCKETS + b] = lh[b];
}

// 2) per-bucket exclusive scan over chunks -> base[b][c], bucketTotal[b]
__global__ __launch_bounds__(256) void scan_chunks_kernel(const int* __restrict__ hist,
                                                          int* __restrict__ base,
                                                          int* __restrict__ bucketTotal) {
    __shared__ int lds[256];
    int b = blockIdx.x;
    int t = threadIdx.x;
    int v[4];
    int s = 0;
    for (int k = 0; k < 4; ++k) {
        int c = 4 * t + k;
        int cv = (c < N_CHUNKS) ? hist[c * N_BUCKETS + b] : 0;
        v[k] = s;
        s += cv;
    }
    lds[t] = s;
    __syncthreads();
    for (int off = 1; off < 256; off <<= 1) {
        int val = (t >= off) ? lds[t - off] : 0;
        __syncthreads();
        lds[t] += val;
        __syncthreads();
    }
    int excl = (t == 0) ? 0 : lds[t - 1];
    for (int k = 0; k < 4; ++k) {
        int c = 4 * t + k;
        if (c < N_CHUNKS) base[b * N_CHUNKS + c] = excl + v[k];
    }
    if (t == 255) bucketTotal[b] = lds[255];
}

// 3) exclusive scan over 782 bucket totals -> bucketBase
__global__ __launch_bounds__(256) void scan_buckets_kernel(const int* __restrict__ bucketTotal,
                                                           int* __restrict__ bucketBase) {
    __shared__ int lds[256];
    int t = threadIdx.x;
    int v[4];
    int s = 0;
    for (int k = 0; k < 4; ++k) {
        int b = 4 * t + k;
        int cv = (b < N_BUCKETS) ? bucketTotal[b] : 0;
        v[k] = s;
        s += cv;
    }
    lds[t] = s;
    __syncthreads();
    for (int off = 1; off < 256; off <<= 1) {
        int val = (t >= off) ? lds[t - off] : 0;
        __syncthreads();
        lds[t] += val;
        __syncthreads();
    }
    int excl = (t == 0) ? 0 : lds[t - 1];
    for (int k = 0; k < 4; ++k) {
        int b = 4 * t + k;
        if (b < N_BUCKETS) bucketBase[b] = excl + v[k];
    }
}

// 4) deterministic scatter into bucket-grouped stage; LDS slice counters only.
//    chunk swizzle keeps adjacent slices on one XCD (round-robin heuristic, speed-only).
__global__ __launch_bounds__(256) void scatter_kernel(const int* __restrict__ src,
                                                      const int* __restrict__ dst,
                                                      const int* __restrict__ base,
                                                      const int* __restrict__ bucketBase,
                                                      int* __restrict__ stage) {
    __shared__ int lbase[N_BUCKETS];
    __shared__ int lcnt[N_BUCKETS];
    int bid = blockIdx.x;
    int chunk = (bid & 7) * 98 + (bid >> 3);   // bijection on [0,784)
    int t = threadIdx.x;
    for (int b = t; b < N_BUCKETS; b += 256) {
        lbase[b] = base[b * N_CHUNKS + chunk] + bucketBase[b];
        lcnt[b] = 0;
    }
    __syncthreads();
    int e0 = chunk * CHUNK;
    for (int i = t; i < CHUNK; i += 256) {
        int e = e0 + i;
        if (e < N_EDGES) {
            int d = dst[e];
            int b = d >> BUCKET_SHIFT;
            int pos = lbase[b] + atomicAdd(&lcnt[b], 1);
            stage[pos] = ((d & (BUCKET_NODES - 1)) << 17) | src[e];
        }
    }
}

// 5) one block per bucket: LDS node histogram + scan -> row_start/cnt/dinv + csr place
__global__ __launch_bounds__(256) void place_kernel(const int* __restrict__ stage,
                                                    const int* __restrict__ bucketBase,
                                                    int* __restrict__ csr,
                                                    int* __restrict__ row_start,
                                                    int* __restrict__ cnt,
                                                    float* __restrict__ dinv) {
    __shared__ int lhist[BUCKET_NODES];
    __shared__ int lscan[BUCKET_NODES];
    __shared__ int lstart[BUCKET_NODES];
    __shared__ int lcur[BUCKET_NODES];
    int b = blockIdx.x;
    int t = threadIdx.x;
    int est = bucketBase[b];
    int een = (b == N_BUCKETS - 1) ? N_EDGES : bucketBase[b + 1];
    if (t < BUCKET_NODES) { lhist[t] = 0; lcur[t] = 0; }
    __syncthreads();
    for (int e = est + t; e < een; e += 256) atomicAdd(&lhist[stage[e] >> 17], 1);
    __syncthreads();
    if (t < BUCKET_NODES) lscan[t] = lhist[t];
    __syncthreads();
    for (int off = 1; off < BUCKET_NODES; off <<= 1) {
        int val = (t >= off && t < BUCKET_NODES) ? lscan[t - off] : 0;
        __syncthreads();
        if (t < BUCKET_NODES) lscan[t] += val;
        __syncthreads();
    }
    if (t < BUCKET_NODES) {
        int myexcl = (t == 0) ? 0 : lscan[t - 1];
        lstart[t] = est + myexcl;
        int node = (b << BUCKET_SHIFT) + t;
        if (node < N_NODES) {
            row_start[node] = est + myexcl;
            cnt[node] = lhist[t];
            dinv[node] = rsqrtf((float)lhist[t] + 1.0f);
        }
    }
    __syncthreads();
    for (int e = est + t; e < een; e += 256) {
        int rec = stage[e];
        int dl = rec >> 17;
        int pos = lstart[dl] + atomicAdd(&lcur[dl], 1);
        csr[pos] = rec & 0x1FFFF;
    }
}

// ---------------- gemm1: h1p[i][j] = f16( dinv[i] * sum_k x[i][k] * W1[k][j] ) ----------------
#define G1_XS 36
__global__ __launch_bounds__(256) void gemm1_kernel(const float* __restrict__ x,
                                                    const float* __restrict__ W1,
                                                    const float* __restrict__ dinv,
                                                    f16* __restrict__ h1p) {
    __shared__ float ws[IN_DIM * HID_DIM];   // 32 KB
    __shared__ float xT[IN_DIM * G1_XS];     // 18 KB
    int t = threadIdx.x;
    int nodeBase = blockIdx.x * 32;

    const float4* W4 = (const float4*)W1;
    float4* ws4 = (float4*)ws;
#pragma unroll
    for (int i = 0; i < 8; ++i) ws4[t + 256 * i] = W4[t + 256 * i];

    int kg = t & 31;
    int nd = t >> 5;
#pragma unroll
    for (int m = 0; m < 4; ++m) {
        int node = nd + 8 * m;
        const float* xr = x + (size_t)(nodeBase + node) * IN_DIM;
#pragma unroll
        for (int j = 0; j < 4; ++j) {
            xT[(kg + 32 * j) * G1_XS + node] = xr[kg + 32 * j];
        }
    }
    __syncthreads();

    int g = t >> 5;   // node group of 4
    int c = t & 31;   // col group of 2
    float a00 = 0.f, a01 = 0.f, a10 = 0.f, a11 = 0.f;
    float a20 = 0.f, a21 = 0.f, a30 = 0.f, a31 = 0.f;
#pragma unroll 4
    for (int k = 0; k < IN_DIM; ++k) {
        float4 xv = *(const float4*)&xT[k * G1_XS + 4 * g];
        float2 wv = *(const float2*)&ws[k * HID_DIM + 2 * c];
        a00 += xv.x * wv.x; a01 += xv.x * wv.y;
        a10 += xv.y * wv.x; a11 += xv.y * wv.y;
        a20 += xv.z * wv.x; a21 += xv.z * wv.y;
        a30 += xv.w * wv.x; a31 += xv.w * wv.y;
    }
    float r0[4] = {a00, a10, a20, a30};
    float r1[4] = {a01, a11, a21, a31};
#pragma unroll
    for (int i = 0; i < 4; ++i) {
        int n = nodeBase + 4 * g + i;
        float di = dinv[n];
        f16x2 o;
        o.x = (f16)(r0[i] * di);
        o.y = (f16)(r1[i] * di);
        *(f16x2*)&h1p[(size_t)n * HID_DIM + 2 * c] = o;
    }
}

// one wave per node: lanes = 64 hidden dims; gather-sum fp16 neighbor rows (fp32 acc)
__global__ __launch_bounds__(256) void agg1_kernel(const f16* __restrict__ h1p,
                                                   const int* __restrict__ csr,
                                                   const int* __restrict__ row_start,
                                                   const int* __restrict__ cnt,
                                                   const float* __restrict__ dinv,
                                                   const float* __restrict__ b1,
                                                   float* __restrict__ z) {
    int w = blockIdx.x * 4 + (threadIdx.x >> 6);
    int j = threadIdx.x & 63;
    if (w >= N_NODES) return;
    int s0 = row_start[w];
    int n  = cnt[w];
    const int* cp = csr + s0;
    float acc = (float)h1p[(size_t)w * HID_DIM + j];   // self loop
    int k = 0;
    for (; k + 4 <= n; k += 4) {
        int a = cp[k], b = cp[k + 1], c = cp[k + 2], d = cp[k + 3];
        float f0 = (float)h1p[(size_t)a * HID_DIM + j];
        float f1 = (float)h1p[(size_t)b * HID_DIM + j];
        float f2 = (float)h1p[(size_t)c * HID_DIM + j];
        float f3 = (float)h1p[(size_t)d * HID_DIM + j];
        acc += f0 + f1 + f2 + f3;
    }
    for (; k < n; ++k) acc += (float)h1p[(size_t)cp[k] * HID_DIM + j];
    float v = acc * dinv[w] + b1[j];
    z[(size_t)w * HID_DIM + j] = v > 0.f ? v : 0.f;
}

// ---------------- gemm2: h2p[i][j] = f16( dinv[i] * sum_k z[i][k] * W2[k][j] ) ----------------
#define G2_ZS 68
__global__ __launch_bounds__(256) void gemm2_kernel(const float* __restrict__ z,
                                                    const float* __restrict__ W2,
                                                    const float* __restrict__ dinv,
                                                    f16* __restrict__ h2p) {
    __shared__ float ws[HID_DIM * OUT_DIM];  // 2560 floats
    __shared__ float zT[HID_DIM * G2_ZS];    // 4352 floats
    int t = threadIdx.x;
    int nodeBase = blockIdx.x * 64;

    const float4* W4 = (const float4*)W2;
    float4* ws4 = (float4*)ws;
    for (int i = t; i < (HID_DIM * OUT_DIM) / 4; i += 256) ws4[i] = W4[i];

    int kg = t & 31;
    int nd = t >> 5;
#pragma unroll
    for (int m = 0; m < 8; ++m) {
        int node = nd + 8 * m;
        int n = nodeBase + node;
        float v0 = 0.f, v1 = 0.f;
        if (n < N_NODES) {
            const float* zr = z + (size_t)n * HID_DIM;
            v0 = zr[kg];
            v1 = zr[kg + 32];
        }
        zT[kg * G2_ZS + node] = v0;
        zT[(kg + 32) * G2_ZS + node] = v1;
    }
    __syncthreads();

    int g = t >> 4;   // node group of 4
    int c = t & 15;   // col group of 4; active c<10
    if (c < 10) {
        float acc[4][4] = {};
#pragma unroll 4
        for (int k = 0; k < HID_DIM; ++k) {
            float4 zv = *(const float4*)&zT[k * G2_ZS + 4 * g];
            float4 wv = *(const float4*)&ws[k * OUT_DIM + 4 * c];
            acc[0][0] += zv.x * wv.x; acc[0][1] += zv.x * wv.y; acc[0][2] += zv.x * wv.z; acc[0][3] += zv.x * wv.w;
            acc[1][0] += zv.y * wv.x; acc[1][1] += zv.y * wv.y; acc[1][2] += zv.y * wv.z; acc[1][3] += zv.y * wv.w;
            acc[2][0] += zv.z * wv.x; acc[2][1] += zv.z * wv.y; acc[2][2] += zv.z * wv.z; acc[2][3] += zv.z * wv.w;
            acc[3][0] += zv.w * wv.x; acc[3][1] += zv.w * wv.y; acc[3][2] += zv.w * wv.z; acc[3][3] += zv.w * wv.w;
        }
#pragma unroll
        for (int i = 0; i < 4; ++i) {
            int n = nodeBase + 4 * g + i;
            if (n < N_NODES) {
                float di = dinv[n];
                f16x4 o;
                o.x = (f16)(acc[i][0] * di);
                o.y = (f16)(acc[i][1] * di);
                o.z = (f16)(acc[i][2] * di);
                o.w = (f16)(acc[i][3] * di);
                *(f16x4*)&h2p[(size_t)n * OUT_DIM + 4 * c] = o;
            }
        }
    }
}

// one wave per node, lanes 0..39 = out dims; fp16 gather, fp32 acc
__global__ __launch_bounds__(256) void agg2_kernel(const f16* __restrict__ h2p,
                                                   const int* __restrict__ csr,
                                                   const int* __restrict__ row_start,
                                                   const int* __restrict__ cnt,
                                                   const float* __restrict__ dinv,
                                                   const float* __restrict__ b2,
                                                   float* __restrict__ out) {
    int w = blockIdx.x * 4 + (threadIdx.x >> 6);
    int j = threadIdx.x & 63;
    if (w >= N_NODES || j >= OUT_DIM) return;
    int s0 = row_start[w];
    int n  = cnt[w];
    const int* cp = csr + s0;
    float acc = (float)h2p[(size_t)w * OUT_DIM + j];   // self loop
    int k = 0;
    for (; k + 4 <= n; k += 4) {
        int a = cp[k], b = cp[k + 1], c = cp[k + 2], d = cp[k + 3];
        float f0 = (float)h2p[(size_t)a * OUT_DIM + j];
        float f1 = (float)h2p[(size_t)b * OUT_DIM + j];
        float f2 = (float)h2p[(size_t)c * OUT_DIM + j];
        float f3 = (float)h2p[(size_t)d * OUT_DIM + j];
        acc += f0 + f1 + f2 + f3;
    }
    for (; k < n; ++k) acc += (float)h2p[(size_t)cp[k] * OUT_DIM + j];
    out[(size_t)w * OUT_DIM + j] = acc * dinv[w] + b2[j];
}

extern "C" void kernel_launch(void* const* d_in, const int* in_sizes, int n_in,
                              void* d_out, int out_size, void* d_ws, size_t ws_size,
                              hipStream_t stream) {
    const float* x  = (const float*)d_in[0];
    const int*   ei = (const int*)d_in[1];      // [2, E] int32
    const float* W1 = (const float*)d_in[2];
    const float* b1 = (const float*)d_in[3];
    const float* W2 = (const float*)d_in[4];
    const float* b2 = (const float*)d_in[5];
    float* out = (float*)d_out;

    const int* src = ei;
    const int* dst = ei + N_EDGES;

    int* wsi        = (int*)d_ws;
    int* hist       = wsi;
    int* base       = hist + N_CHUNKS * N_BUCKETS;
    int* bucketTotal= base + N_BUCKETS * N_CHUNKS;
    int* bucketBase = bucketTotal + 1024;
    int* row_start  = bucketBase + 1024;
    int* cnt        = row_start + NPAD;
    int* csr        = cnt + NPAD;
    int* stage      = csr + N_EDGES;
    float* dinv     = (float*)(stage + N_EDGES);
    float* z        = dinv + NPAD;
    f16*   h1p      = (f16*)(z + (size_t)N_NODES * HID_DIM);
    f16*   h2p      = h1p + (size_t)N_NODES * HID_DIM;

    hist_kernel<<<N_CHUNKS, 256, 0, stream>>>(dst, hist);
    scan_chunks_kernel<<<N_BUCKETS, 256, 0, stream>>>(hist, base, bucketTotal);
    scan_buckets_kernel<<<1, 256, 0, stream>>>(bucketTotal, bucketBase);
    scatter_kernel<<<N_CHUNKS, 256, 0, stream>>>(src, dst, base, bucketBase, stage);
    place_kernel<<<N_BUCKETS, 256, 0, stream>>>(stage, bucketBase, csr, row_start, cnt, dinv);

    gemm1_kernel<<<N_NODES / 32, 256, 0, stream>>>(x, W1, dinv, h1p);
    agg1_kernel<<<(N_NODES + 3) / 4, 256, 0, stream>>>(h1p, csr, row_start, cnt, dinv, b1, z);
    gemm2_kernel<<<(N_NODES + 63) / 64, 256, 0, stream>>>(z, W2, dinv, h2p);
    agg2_kernel<<<(N_NODES + 3) / 4, 256, 0, stream>>>(h2p, csr, row_start, cnt, dinv, b2, out);
}

// Round 8
// 257.885 us; speedup vs baseline: 2.8416x; 1.1876x over previous
//
#include <hip/hip_runtime.h>
#include <math.h>

#define N_NODES 100000
#define N_EDGES 1600000
#define IN_DIM 128
#define HID_DIM 64
#define OUT_DIM 40

#define NPAD 102400

#define BUCKET_SHIFT 7
#define BUCKET_NODES 128
#define N_BUCKETS 782          // ceil(100000/128)
#define CHUNK 2048
#define N_CHUNKS 784           // 8 XCD groups x 98; 784*2048 >= N_EDGES

typedef _Float16 f16;
typedef _Float16 f16x2 __attribute__((ext_vector_type(2)));
typedef _Float16 f16x4 __attribute__((ext_vector_type(4)));

// -------- workspace layout --------
// ints:  hist[N_CHUNKS*N_BUCKETS] | base[N_BUCKETS*N_CHUNKS] | bucketTotal[1024] |
//        bucketBase[1024] | row_start[NPAD] | cnt[NPAD] | csr[E] | stage[E]
// floats: dinv[NPAD] | z[N*64]
// f16:    h1p[N*64] | h2p[N*40]
// NO memset needed: every buffer fully written before read each launch.

// 1) per-chunk LDS histogram over dst buckets; coalesced row write
__global__ __launch_bounds__(256) void hist_kernel(const int* __restrict__ dst,
                                                   int* __restrict__ hist) {
    __shared__ int lh[N_BUCKETS];
    int c = blockIdx.x;
    int t = threadIdx.x;
    for (int b = t; b < N_BUCKETS; b += 256) lh[b] = 0;
    __syncthreads();
    int e0 = c * CHUNK;
    for (int i = t; i < CHUNK; i += 256) {
        int e = e0 + i;
        if (e < N_EDGES) atomicAdd(&lh[dst[e] >> BUCKET_SHIFT], 1);
    }
    __syncthreads();
    for (int b = t; b < N_BUCKETS; b += 256) hist[c * N_BUCKETS + b] = lh[b];
}

// 2) per-bucket exclusive scan over chunks -> base[b][c], bucketTotal[b]
__global__ __launch_bounds__(256) void scan_chunks_kernel(const int* __restrict__ hist,
                                                          int* __restrict__ base,
                                                          int* __restrict__ bucketTotal) {
    __shared__ int lds[256];
    int b = blockIdx.x;
    int t = threadIdx.x;
    int v[4];
    int s = 0;
    for (int k = 0; k < 4; ++k) {
        int c = 4 * t + k;
        int cv = (c < N_CHUNKS) ? hist[c * N_BUCKETS + b] : 0;
        v[k] = s;
        s += cv;
    }
    lds[t] = s;
    __syncthreads();
    for (int off = 1; off < 256; off <<= 1) {
        int val = (t >= off) ? lds[t - off] : 0;
        __syncthreads();
        lds[t] += val;
        __syncthreads();
    }
    int excl = (t == 0) ? 0 : lds[t - 1];
    for (int k = 0; k < 4; ++k) {
        int c = 4 * t + k;
        if (c < N_CHUNKS) base[b * N_CHUNKS + c] = excl + v[k];
    }
    if (t == 255) bucketTotal[b] = lds[255];
}

// 3) exclusive scan over 782 bucket totals -> bucketBase
__global__ __launch_bounds__(256) void scan_buckets_kernel(const int* __restrict__ bucketTotal,
                                                           int* __restrict__ bucketBase) {
    __shared__ int lds[256];
    int t = threadIdx.x;
    int v[4];
    int s = 0;
    for (int k = 0; k < 4; ++k) {
        int b = 4 * t + k;
        int cv = (b < N_BUCKETS) ? bucketTotal[b] : 0;
        v[k] = s;
        s += cv;
    }
    lds[t] = s;
    __syncthreads();
    for (int off = 1; off < 256; off <<= 1) {
        int val = (t >= off) ? lds[t - off] : 0;
        __syncthreads();
        lds[t] += val;
        __syncthreads();
    }
    int excl = (t == 0) ? 0 : lds[t - 1];
    for (int k = 0; k < 4; ++k) {
        int b = 4 * t + k;
        if (b < N_BUCKETS) bucketBase[b] = excl + v[k];
    }
}

// 4) deterministic scatter into bucket-grouped stage; LDS slice counters only.
__global__ __launch_bounds__(256) void scatter_kernel(const int* __restrict__ src,
                                                      const int* __restrict__ dst,
                                                      const int* __restrict__ base,
                                                      const int* __restrict__ bucketBase,
                                                      int* __restrict__ stage) {
    __shared__ int lbase[N_BUCKETS];
    __shared__ int lcnt[N_BUCKETS];
    int bid = blockIdx.x;
    int chunk = (bid & 7) * 98 + (bid >> 3);   // bijection on [0,784)
    int t = threadIdx.x;
    for (int b = t; b < N_BUCKETS; b += 256) {
        lbase[b] = base[b * N_CHUNKS + chunk] + bucketBase[b];
        lcnt[b] = 0;
    }
    __syncthreads();
    int e0 = chunk * CHUNK;
    for (int i = t; i < CHUNK; i += 256) {
        int e = e0 + i;
        if (e < N_EDGES) {
            int d = dst[e];
            int b = d >> BUCKET_SHIFT;
            int pos = lbase[b] + atomicAdd(&lcnt[b], 1);
            stage[pos] = ((d & (BUCKET_NODES - 1)) << 17) | src[e];
        }
    }
}

// 5) one block per bucket: LDS node histogram + scan -> row_start/cnt/dinv + csr place
__global__ __launch_bounds__(256) void place_kernel(const int* __restrict__ stage,
                                                    const int* __restrict__ bucketBase,
                                                    int* __restrict__ csr,
                                                    int* __restrict__ row_start,
                                                    int* __restrict__ cnt,
                                                    float* __restrict__ dinv) {
    __shared__ int lhist[BUCKET_NODES];
    __shared__ int lscan[BUCKET_NODES];
    __shared__ int lstart[BUCKET_NODES];
    __shared__ int lcur[BUCKET_NODES];
    int b = blockIdx.x;
    int t = threadIdx.x;
    int est = bucketBase[b];
    int een = (b == N_BUCKETS - 1) ? N_EDGES : bucketBase[b + 1];
    if (t < BUCKET_NODES) { lhist[t] = 0; lcur[t] = 0; }
    __syncthreads();
    for (int e = est + t; e < een; e += 256) atomicAdd(&lhist[stage[e] >> 17], 1);
    __syncthreads();
    if (t < BUCKET_NODES) lscan[t] = lhist[t];
    __syncthreads();
    for (int off = 1; off < BUCKET_NODES; off <<= 1) {
        int val = (t >= off && t < BUCKET_NODES) ? lscan[t - off] : 0;
        __syncthreads();
        if (t < BUCKET_NODES) lscan[t] += val;
        __syncthreads();
    }
    if (t < BUCKET_NODES) {
        int myexcl = (t == 0) ? 0 : lscan[t - 1];
        lstart[t] = est + myexcl;
        int node = (b << BUCKET_SHIFT) + t;
        if (node < N_NODES) {
            row_start[node] = est + myexcl;
            cnt[node] = lhist[t];
            dinv[node] = rsqrtf((float)lhist[t] + 1.0f);
        }
    }
    __syncthreads();
    for (int e = est + t; e < een; e += 256) {
        int rec = stage[e];
        int dl = rec >> 17;
        int pos = lstart[dl] + atomicAdd(&lcur[dl], 1);
        csr[pos] = rec & 0x1FFFF;
    }
}

// ---------------- gemm1: h1p[i][j] = f16( dinv[i] * sum_k x[i][k] * W1[k][j] ) ----------------
#define G1_XS 36
__global__ __launch_bounds__(256) void gemm1_kernel(const float* __restrict__ x,
                                                    const float* __restrict__ W1,
                                                    const float* __restrict__ dinv,
                                                    f16* __restrict__ h1p) {
    __shared__ float ws[IN_DIM * HID_DIM];   // 32 KB
    __shared__ float xT[IN_DIM * G1_XS];     // 18 KB
    int t = threadIdx.x;
    int nodeBase = blockIdx.x * 32;

    const float4* W4 = (const float4*)W1;
    float4* ws4 = (float4*)ws;
#pragma unroll
    for (int i = 0; i < 8; ++i) ws4[t + 256 * i] = W4[t + 256 * i];

    int kg = t & 31;
    int nd = t >> 5;
#pragma unroll
    for (int m = 0; m < 4; ++m) {
        int node = nd + 8 * m;
        const float* xr = x + (size_t)(nodeBase + node) * IN_DIM;
#pragma unroll
        for (int j = 0; j < 4; ++j) {
            xT[(kg + 32 * j) * G1_XS + node] = xr[kg + 32 * j];
        }
    }
    __syncthreads();

    int g = t >> 5;   // node group of 4
    int c = t & 31;   // col group of 2
    float a00 = 0.f, a01 = 0.f, a10 = 0.f, a11 = 0.f;
    float a20 = 0.f, a21 = 0.f, a30 = 0.f, a31 = 0.f;
#pragma unroll 4
    for (int k = 0; k < IN_DIM; ++k) {
        float4 xv = *(const float4*)&xT[k * G1_XS + 4 * g];
        float2 wv = *(const float2*)&ws[k * HID_DIM + 2 * c];
        a00 += xv.x * wv.x; a01 += xv.x * wv.y;
        a10 += xv.y * wv.x; a11 += xv.y * wv.y;
        a20 += xv.z * wv.x; a21 += xv.z * wv.y;
        a30 += xv.w * wv.x; a31 += xv.w * wv.y;
    }
    float r0[4] = {a00, a10, a20, a30};
    float r1[4] = {a01, a11, a21, a31};
#pragma unroll
    for (int i = 0; i < 4; ++i) {
        int n = nodeBase + 4 * g + i;
        float di = dinv[n];
        f16x2 o;
        o.x = (f16)(r0[i] * di);
        o.y = (f16)(r1[i] * di);
        *(f16x2*)&h1p[(size_t)n * HID_DIM + 2 * c] = o;
    }
}

// agg1: 2 nodes per wave (32-lane halves), lane gathers f16x2 (4B); unroll 4 with
// index prefetch -> 8 cache lines in flight per wave. fp32 accumulate.
__global__ __launch_bounds__(256) void agg1_kernel(const f16* __restrict__ h1p,
                                                   const int* __restrict__ csr,
                                                   const int* __restrict__ row_start,
                                                   const int* __restrict__ cnt,
                                                   const float* __restrict__ dinv,
                                                   const float* __restrict__ b1,
                                                   float* __restrict__ z) {
    int node = blockIdx.x * 8 + (threadIdx.x >> 5);
    int lane = threadIdx.x & 31;          // f16x2 slot: dims 2*lane, 2*lane+1
    if (node >= N_NODES) return;
    const f16x2* h = (const f16x2*)h1p;   // row stride 32 (f16x2 units)
    float2 acc;
    {
        f16x2 sv = h[(size_t)node * 32 + lane];   // self loop
        acc.x = (float)sv.x;
        acc.y = (float)sv.y;
    }
    int n = cnt[node];
    const int* cp = csr + row_start[node];
    int k = 0;
    if (n >= 4) {
        int i0 = cp[0], i1 = cp[1], i2 = cp[2], i3 = cp[3];
        for (; k + 8 <= n; k += 4) {
            int j0 = cp[k + 4], j1 = cp[k + 5], j2 = cp[k + 6], j3 = cp[k + 7];
            f16x2 f0 = h[(size_t)i0 * 32 + lane];
            f16x2 f1 = h[(size_t)i1 * 32 + lane];
            f16x2 f2 = h[(size_t)i2 * 32 + lane];
            f16x2 f3 = h[(size_t)i3 * 32 + lane];
            acc.x += (float)f0.x + (float)f1.x + (float)f2.x + (float)f3.x;
            acc.y += (float)f0.y + (float)f1.y + (float)f2.y + (float)f3.y;
            i0 = j0; i1 = j1; i2 = j2; i3 = j3;
        }
        {
            f16x2 f0 = h[(size_t)i0 * 32 + lane];
            f16x2 f1 = h[(size_t)i1 * 32 + lane];
            f16x2 f2 = h[(size_t)i2 * 32 + lane];
            f16x2 f3 = h[(size_t)i3 * 32 + lane];
            acc.x += (float)f0.x + (float)f1.x + (float)f2.x + (float)f3.x;
            acc.y += (float)f0.y + (float)f1.y + (float)f2.y + (float)f3.y;
            k += 4;
        }
    }
    for (; k < n; ++k) {
        f16x2 f = h[(size_t)cp[k] * 32 + lane];
        acc.x += (float)f.x;
        acc.y += (float)f.y;
    }
    float di = dinv[node];
    float2 bb = *(const float2*)&b1[2 * lane];
    float v0 = acc.x * di + bb.x;
    float v1 = acc.y * di + bb.y;
    float2 o;
    o.x = v0 > 0.f ? v0 : 0.f;
    o.y = v1 > 0.f ? v1 : 0.f;
    *(float2*)&z[(size_t)node * HID_DIM + 2 * lane] = o;
}

// ---------------- gemm2: h2p[i][j] = f16( dinv[i] * sum_k z[i][k] * W2[k][j] ) ----------------
#define G2_ZS 68
__global__ __launch_bounds__(256) void gemm2_kernel(const float* __restrict__ z,
                                                    const float* __restrict__ W2,
                                                    const float* __restrict__ dinv,
                                                    f16* __restrict__ h2p) {
    __shared__ float ws[HID_DIM * OUT_DIM];  // 2560 floats
    __shared__ float zT[HID_DIM * G2_ZS];    // 4352 floats
    int t = threadIdx.x;
    int nodeBase = blockIdx.x * 64;

    const float4* W4 = (const float4*)W2;
    float4* ws4 = (float4*)ws;
    for (int i = t; i < (HID_DIM * OUT_DIM) / 4; i += 256) ws4[i] = W4[i];

    int kg = t & 31;
    int nd = t >> 5;
#pragma unroll
    for (int m = 0; m < 8; ++m) {
        int node = nd + 8 * m;
        int n = nodeBase + node;
        float v0 = 0.f, v1 = 0.f;
        if (n < N_NODES) {
            const float* zr = z + (size_t)n * HID_DIM;
            v0 = zr[kg];
            v1 = zr[kg + 32];
        }
        zT[kg * G2_ZS + node] = v0;
        zT[(kg + 32) * G2_ZS + node] = v1;
    }
    __syncthreads();

    int g = t >> 4;   // node group of 4
    int c = t & 15;   // col group of 4; active c<10
    if (c < 10) {
        float acc[4][4] = {};
#pragma unroll 4
        for (int k = 0; k < HID_DIM; ++k) {
            float4 zv = *(const float4*)&zT[k * G2_ZS + 4 * g];
            float4 wv = *(const float4*)&ws[k * OUT_DIM + 4 * c];
            acc[0][0] += zv.x * wv.x; acc[0][1] += zv.x * wv.y; acc[0][2] += zv.x * wv.z; acc[0][3] += zv.x * wv.w;
            acc[1][0] += zv.y * wv.x; acc[1][1] += zv.y * wv.y; acc[1][2] += zv.y * wv.z; acc[1][3] += zv.y * wv.w;
            acc[2][0] += zv.z * wv.x; acc[2][1] += zv.z * wv.y; acc[2][2] += zv.z * wv.z; acc[2][3] += zv.z * wv.w;
            acc[3][0] += zv.w * wv.x; acc[3][1] += zv.w * wv.y; acc[3][2] += zv.w * wv.z; acc[3][3] += zv.w * wv.w;
        }
#pragma unroll
        for (int i = 0; i < 4; ++i) {
            int n = nodeBase + 4 * g + i;
            if (n < N_NODES) {
                float di = dinv[n];
                f16x4 o;
                o.x = (f16)(acc[i][0] * di);
                o.y = (f16)(acc[i][1] * di);
                o.z = (f16)(acc[i][2] * di);
                o.w = (f16)(acc[i][3] * di);
                *(f16x4*)&h2p[(size_t)n * OUT_DIM + 4 * c] = o;
            }
        }
    }
}

// agg2: 2 nodes per wave (32-lane halves), lanes 0..19 gather f16x2; unroll 4 + prefetch
__global__ __launch_bounds__(256) void agg2_kernel(const f16* __restrict__ h2p,
                                                   const int* __restrict__ csr,
                                                   const int* __restrict__ row_start,
                                                   const int* __restrict__ cnt,
                                                   const float* __restrict__ dinv,
                                                   const float* __restrict__ b2,
                                                   float* __restrict__ out) {
    int node = blockIdx.x * 8 + (threadIdx.x >> 5);
    int lane = threadIdx.x & 31;          // f16x2 slot: dims 2*lane, 2*lane+1 (active <20)
    if (node >= N_NODES || lane >= 20) return;
    const f16x2* h = (const f16x2*)h2p;   // row stride 20 (f16x2 units)
    float2 acc;
    {
        f16x2 sv = h[(size_t)node * 20 + lane];   // self loop
        acc.x = (float)sv.x;
        acc.y = (float)sv.y;
    }
    int n = cnt[node];
    const int* cp = csr + row_start[node];
    int k = 0;
    if (n >= 4) {
        int i0 = cp[0], i1 = cp[1], i2 = cp[2], i3 = cp[3];
        for (; k + 8 <= n; k += 4) {
            int j0 = cp[k + 4], j1 = cp[k + 5], j2 = cp[k + 6], j3 = cp[k + 7];
            f16x2 f0 = h[(size_t)i0 * 20 + lane];
            f16x2 f1 = h[(size_t)i1 * 20 + lane];
            f16x2 f2 = h[(size_t)i2 * 20 + lane];
            f16x2 f3 = h[(size_t)i3 * 20 + lane];
            acc.x += (float)f0.x + (float)f1.x + (float)f2.x + (float)f3.x;
            acc.y += (float)f0.y + (float)f1.y + (float)f2.y + (float)f3.y;
            i0 = j0; i1 = j1; i2 = j2; i3 = j3;
        }
        {
            f16x2 f0 = h[(size_t)i0 * 20 + lane];
            f16x2 f1 = h[(size_t)i1 * 20 + lane];
            f16x2 f2 = h[(size_t)i2 * 20 + lane];
            f16x2 f3 = h[(size_t)i3 * 20 + lane];
            acc.x += (float)f0.x + (float)f1.x + (float)f2.x + (float)f3.x;
            acc.y += (float)f0.y + (float)f1.y + (float)f2.y + (float)f3.y;
            k += 4;
        }
    }
    for (; k < n; ++k) {
        f16x2 f = h[(size_t)cp[k] * 20 + lane];
        acc.x += (float)f.x;
        acc.y += (float)f.y;
    }
    float di = dinv[node];
    float2 bb = *(const float2*)&b2[2 * lane];
    float2 o;
    o.x = acc.x * di + bb.x;
    o.y = acc.y * di + bb.y;
    *(float2*)&out[(size_t)node * OUT_DIM + 2 * lane] = o;
}

extern "C" void kernel_launch(void* const* d_in, const int* in_sizes, int n_in,
                              void* d_out, int out_size, void* d_ws, size_t ws_size,
                              hipStream_t stream) {
    const float* x  = (const float*)d_in[0];
    const int*   ei = (const int*)d_in[1];      // [2, E] int32
    const float* W1 = (const float*)d_in[2];
    const float* b1 = (const float*)d_in[3];
    const float* W2 = (const float*)d_in[4];
    const float* b2 = (const float*)d_in[5];
    float* out = (float*)d_out;

    const int* src = ei;
    const int* dst = ei + N_EDGES;

    int* wsi        = (int*)d_ws;
    int* hist       = wsi;
    int* base       = hist + N_CHUNKS * N_BUCKETS;
    int* bucketTotal= base + N_BUCKETS * N_CHUNKS;
    int* bucketBase = bucketTotal + 1024;
    int* row_start  = bucketBase + 1024;
    int* cnt        = row_start + NPAD;
    int* csr        = cnt + NPAD;
    int* stage      = csr + N_EDGES;
    float* dinv     = (float*)(stage + N_EDGES);
    float* z        = dinv + NPAD;
    f16*   h1p      = (f16*)(z + (size_t)N_NODES * HID_DIM);
    f16*   h2p      = h1p + (size_t)N_NODES * HID_DIM;

    hist_kernel<<<N_CHUNKS, 256, 0, stream>>>(dst, hist);
    scan_chunks_kernel<<<N_BUCKETS, 256, 0, stream>>>(hist, base, bucketTotal);
    scan_buckets_kernel<<<1, 256, 0, stream>>>(bucketTotal, bucketBase);
    scatter_kernel<<<N_CHUNKS, 256, 0, stream>>>(src, dst, base, bucketBase, stage);
    place_kernel<<<N_BUCKETS, 256, 0, stream>>>(stage, bucketBase, csr, row_start, cnt, dinv);

    gemm1_kernel<<<N_NODES / 32, 256, 0, stream>>>(x, W1, dinv, h1p);
    agg1_kernel<<<(N_NODES + 7) / 8, 256, 0, stream>>>(h1p, csr, row_start, cnt, dinv, b1, z);
    gemm2_kernel<<<(N_NODES + 63) / 64, 256, 0, stream>>>(z, W2, dinv, h2p);
    agg2_kernel<<<(N_NODES + 7) / 8, 256, 0, stream>>>(h2p, csr, row_start, cnt, dinv, b2, out);
}

// Round 9
// 239.582 us; speedup vs baseline: 3.0587x; 1.0764x over previous
//
#include <hip/hip_runtime.h>
#include <math.h>

#define N_NODES 100000
#define N_EDGES 1600000
#define IN_DIM 128
#define HID_DIM 64
#define OUT_DIM 40

#define NPAD 102400

#define BUCKET_SHIFT 7
#define BUCKET_NODES 128
#define N_BUCKETS 782          // ceil(100000/128)
#define CHUNK 2048
#define N_CHUNKS 784           // 8 XCD groups x 98; 784*2048 >= N_EDGES

typedef _Float16 f16;
typedef _Float16 f16x2 __attribute__((ext_vector_type(2)));
typedef _Float16 f16x4 __attribute__((ext_vector_type(4)));
typedef _Float16 f16x8 __attribute__((ext_vector_type(8)));
typedef float f32x4 __attribute__((ext_vector_type(4)));

// -------- workspace layout --------
// ints:  hist[N_CHUNKS*N_BUCKETS] | base[N_BUCKETS*N_CHUNKS] | bucketTotal[1024] |
//        bucketBase[1024] | row_start[NPAD] | cnt[NPAD] | csr[E] | stage[E]
// floats: dinv[NPAD] | z[N*64]
// f16:    h1p[N*64] | h2p[N*40] | w1f[8192]
// NO memset needed: every buffer fully written before read each launch.

// 1) per-chunk LDS histogram over dst buckets; coalesced row write
__global__ __launch_bounds__(256) void hist_kernel(const int* __restrict__ dst,
                                                   int* __restrict__ hist) {
    __shared__ int lh[N_BUCKETS];
    int c = blockIdx.x;
    int t = threadIdx.x;
    for (int b = t; b < N_BUCKETS; b += 256) lh[b] = 0;
    __syncthreads();
    int e0 = c * CHUNK;
    for (int i = t; i < CHUNK; i += 256) {
        int e = e0 + i;
        if (e < N_EDGES) atomicAdd(&lh[dst[e] >> BUCKET_SHIFT], 1);
    }
    __syncthreads();
    for (int b = t; b < N_BUCKETS; b += 256) hist[c * N_BUCKETS + b] = lh[b];
}

// 2) per-bucket exclusive scan over chunks -> base[b][c], bucketTotal[b]
__global__ __launch_bounds__(256) void scan_chunks_kernel(const int* __restrict__ hist,
                                                          int* __restrict__ base,
                                                          int* __restrict__ bucketTotal) {
    __shared__ int lds[256];
    int b = blockIdx.x;
    int t = threadIdx.x;
    int v[4];
    int s = 0;
    for (int k = 0; k < 4; ++k) {
        int c = 4 * t + k;
        int cv = (c < N_CHUNKS) ? hist[c * N_BUCKETS + b] : 0;
        v[k] = s;
        s += cv;
    }
    lds[t] = s;
    __syncthreads();
    for (int off = 1; off < 256; off <<= 1) {
        int val = (t >= off) ? lds[t - off] : 0;
        __syncthreads();
        lds[t] += val;
        __syncthreads();
    }
    int excl = (t == 0) ? 0 : lds[t - 1];
    for (int k = 0; k < 4; ++k) {
        int c = 4 * t + k;
        if (c < N_CHUNKS) base[b * N_CHUNKS + c] = excl + v[k];
    }
    if (t == 255) bucketTotal[b] = lds[255];
}

// 3) exclusive scan over 782 bucket totals -> bucketBase
__global__ __launch_bounds__(256) void scan_buckets_kernel(const int* __restrict__ bucketTotal,
                                                           int* __restrict__ bucketBase) {
    __shared__ int lds[256];
    int t = threadIdx.x;
    int v[4];
    int s = 0;
    for (int k = 0; k < 4; ++k) {
        int b = 4 * t + k;
        int cv = (b < N_BUCKETS) ? bucketTotal[b] : 0;
        v[k] = s;
        s += cv;
    }
    lds[t] = s;
    __syncthreads();
    for (int off = 1; off < 256; off <<= 1) {
        int val = (t >= off) ? lds[t - off] : 0;
        __syncthreads();
        lds[t] += val;
        __syncthreads();
    }
    int excl = (t == 0) ? 0 : lds[t - 1];
    for (int k = 0; k < 4; ++k) {
        int b = 4 * t + k;
        if (b < N_BUCKETS) bucketBase[b] = excl + v[k];
    }
}

// 4) deterministic scatter into bucket-grouped stage; LDS slice counters only.
__global__ __launch_bounds__(256) void scatter_kernel(const int* __restrict__ src,
                                                      const int* __restrict__ dst,
                                                      const int* __restrict__ base,
                                                      const int* __restrict__ bucketBase,
                                                      int* __restrict__ stage) {
    __shared__ int lbase[N_BUCKETS];
    __shared__ int lcnt[N_BUCKETS];
    int bid = blockIdx.x;
    int chunk = (bid & 7) * 98 + (bid >> 3);   // bijection on [0,784)
    int t = threadIdx.x;
    for (int b = t; b < N_BUCKETS; b += 256) {
        lbase[b] = base[b * N_CHUNKS + chunk] + bucketBase[b];
        lcnt[b] = 0;
    }
    __syncthreads();
    int e0 = chunk * CHUNK;
    for (int i = t; i < CHUNK; i += 256) {
        int e = e0 + i;
        if (e < N_EDGES) {
            int d = dst[e];
            int b = d >> BUCKET_SHIFT;
            int pos = lbase[b] + atomicAdd(&lcnt[b], 1);
            stage[pos] = ((d & (BUCKET_NODES - 1)) << 17) | src[e];
        }
    }
}

// 5) one block per bucket: LDS node histogram + scan -> row_start/cnt/dinv + csr place
__global__ __launch_bounds__(256) void place_kernel(const int* __restrict__ stage,
                                                    const int* __restrict__ bucketBase,
                                                    int* __restrict__ csr,
                                                    int* __restrict__ row_start,
                                                    int* __restrict__ cnt,
                                                    float* __restrict__ dinv) {
    __shared__ int lhist[BUCKET_NODES];
    __shared__ int lscan[BUCKET_NODES];
    __shared__ int lstart[BUCKET_NODES];
    __shared__ int lcur[BUCKET_NODES];
    int b = blockIdx.x;
    int t = threadIdx.x;
    int est = bucketBase[b];
    int een = (b == N_BUCKETS - 1) ? N_EDGES : bucketBase[b + 1];
    if (t < BUCKET_NODES) { lhist[t] = 0; lcur[t] = 0; }
    __syncthreads();
    for (int e = est + t; e < een; e += 256) atomicAdd(&lhist[stage[e] >> 17], 1);
    __syncthreads();
    if (t < BUCKET_NODES) lscan[t] = lhist[t];
    __syncthreads();
    for (int off = 1; off < BUCKET_NODES; off <<= 1) {
        int val = (t >= off && t < BUCKET_NODES) ? lscan[t - off] : 0;
        __syncthreads();
        if (t < BUCKET_NODES) lscan[t] += val;
        __syncthreads();
    }
    if (t < BUCKET_NODES) {
        int myexcl = (t == 0) ? 0 : lscan[t - 1];
        lstart[t] = est + myexcl;
        int node = (b << BUCKET_SHIFT) + t;
        if (node < N_NODES) {
            row_start[node] = est + myexcl;
            cnt[node] = lhist[t];
            dinv[node] = rsqrtf((float)lhist[t] + 1.0f);
        }
    }
    __syncthreads();
    for (int e = est + t; e < een; e += 256) {
        int rec = stage[e];
        int dl = rec >> 17;
        int pos = lstart[dl] + atomicAdd(&lcur[dl], 1);
        csr[pos] = rec & 0x1FFFF;
    }
}

// ---- W1 -> fragment-ordered f16 (B-operand layout for mfma_f32_16x16x32_f16) ----
// frag f = s*4+c (k-step s, col-tile c); lane L holds B[32s + (L>>4)*8 + j][16c + (L&15)]
// stored as f16x8 at w1f8[f*64 + L].
__global__ __launch_bounds__(256) void w1frag_kernel(const float* __restrict__ W1,
                                                     f16* __restrict__ w1f) {
    int g = blockIdx.x * 256 + threadIdx.x;   // [0,1024)
    int f = g >> 6, L = g & 63;
    int s = f >> 2, c = f & 3;
    int q = L >> 4, n = L & 15;
    f16x8 v;
#pragma unroll
    for (int j = 0; j < 8; ++j) {
        int k = 32 * s + 8 * q + j;
        v[j] = (f16)W1[k * HID_DIM + 16 * c + n];
    }
    *(f16x8*)&w1f[(size_t)g * 8] = v;
}

// ---------------- gemm1 (MFMA): h1p = f16( dinv * (x @ W1) ) ----------------
// 64x64 tile per block (4 waves); A (x) staged to LDS in fragment order with
// 17-unit padding (16B units): idx16 = (w*4+s)*68 + 17*q + m. B-frags in registers.
__global__ __launch_bounds__(256) void gemm1_kernel(const float* __restrict__ x,
                                                    const f16* __restrict__ w1f,
                                                    const float* __restrict__ dinv,
                                                    f16* __restrict__ h1p) {
    __shared__ f16 aT[1088 * 8];   // 17408 B
    int t = threadIdx.x;
    int nodeBase = blockIdx.x * 64;
    int L = t & 63;

    // B fragments -> registers (lane-contiguous, coalesced)
    const f16x8* w1f8 = (const f16x8*)w1f;
    f16x8 bfrag[16];
#pragma unroll
    for (int f = 0; f < 16; ++f) bfrag[f] = w1f8[f * 64 + L];

    // stage A: coalesced float4 reads, cvt f16, swizzled 8B LDS writes
#pragma unroll
    for (int i = 0; i < 8; ++i) {
        int idx = i * 256 + t;
        int node = idx >> 5;
        int col4 = idx & 31;
        int gnode = nodeBase + node;
        if (gnode >= N_NODES) gnode = N_NODES - 1;
        float4 v = *(const float4*)&x[(size_t)gnode * IN_DIM + col4 * 4];
        int w = node >> 4, m = node & 15;
        int s = col4 >> 3, q = (col4 >> 1) & 3, j0 = (col4 & 1) * 4;
        f16x4 h;
        h.x = (f16)v.x; h.y = (f16)v.y; h.z = (f16)v.z; h.w = (f16)v.w;
        int idx16 = (w * 4 + s) * 68 + 17 * q + m;
        *(f16x4*)&aT[idx16 * 8 + j0] = h;
    }
    __syncthreads();

    int wv = t >> 6;
    int q = L >> 4, m = L & 15;
    f32x4 acc[4] = {};
#pragma unroll
    for (int s = 0; s < 4; ++s) {
        f16x8 afrag = *(const f16x8*)&aT[((wv * 4 + s) * 68 + 17 * q + m) * 8];
#pragma unroll
        for (int c = 0; c < 4; ++c)
            acc[c] = __builtin_amdgcn_mfma_f32_16x16x32_f16(afrag, bfrag[s * 4 + c], acc[c], 0, 0, 0);
    }

    // epilogue: D row=(L>>4)*4+r, col=16c+(L&15)
#pragma unroll
    for (int r = 0; r < 4; ++r) {
        int node = nodeBase + 16 * wv + q * 4 + r;
        if (node < N_NODES) {
            float di = dinv[node];
#pragma unroll
            for (int c = 0; c < 4; ++c)
                h1p[(size_t)node * HID_DIM + 16 * c + m] = (f16)(acc[c][r] * di);
        }
    }
}

// agg1: 2 nodes per wave (32-lane halves), lane gathers f16x2 (4B); unroll 4 with
// index prefetch -> 8 cache lines in flight per wave. fp32 accumulate.
__global__ __launch_bounds__(256) void agg1_kernel(const f16* __restrict__ h1p,
                                                   const int* __restrict__ csr,
                                                   const int* __restrict__ row_start,
                                                   const int* __restrict__ cnt,
                                                   const float* __restrict__ dinv,
                                                   const float* __restrict__ b1,
                                                   float* __restrict__ z) {
    int node = blockIdx.x * 8 + (threadIdx.x >> 5);
    int lane = threadIdx.x & 31;          // f16x2 slot: dims 2*lane, 2*lane+1
    if (node >= N_NODES) return;
    const f16x2* h = (const f16x2*)h1p;   // row stride 32 (f16x2 units)
    float2 acc;
    {
        f16x2 sv = h[(size_t)node * 32 + lane];   // self loop
        acc.x = (float)sv.x;
        acc.y = (float)sv.y;
    }
    int n = cnt[node];
    const int* cp = csr + row_start[node];
    int k = 0;
    if (n >= 4) {
        int i0 = cp[0], i1 = cp[1], i2 = cp[2], i3 = cp[3];
        for (; k + 8 <= n; k += 4) {
            int j0 = cp[k + 4], j1 = cp[k + 5], j2 = cp[k + 6], j3 = cp[k + 7];
            f16x2 f0 = h[(size_t)i0 * 32 + lane];
            f16x2 f1 = h[(size_t)i1 * 32 + lane];
            f16x2 f2 = h[(size_t)i2 * 32 + lane];
            f16x2 f3 = h[(size_t)i3 * 32 + lane];
            acc.x += (float)f0.x + (float)f1.x + (float)f2.x + (float)f3.x;
            acc.y += (float)f0.y + (float)f1.y + (float)f2.y + (float)f3.y;
            i0 = j0; i1 = j1; i2 = j2; i3 = j3;
        }
        {
            f16x2 f0 = h[(size_t)i0 * 32 + lane];
            f16x2 f1 = h[(size_t)i1 * 32 + lane];
            f16x2 f2 = h[(size_t)i2 * 32 + lane];
            f16x2 f3 = h[(size_t)i3 * 32 + lane];
            acc.x += (float)f0.x + (float)f1.x + (float)f2.x + (float)f3.x;
            acc.y += (float)f0.y + (float)f1.y + (float)f2.y + (float)f3.y;
            k += 4;
        }
    }
    for (; k < n; ++k) {
        f16x2 f = h[(size_t)cp[k] * 32 + lane];
        acc.x += (float)f.x;
        acc.y += (float)f.y;
    }
    float di = dinv[node];
    float2 bb = *(const float2*)&b1[2 * lane];
    float v0 = acc.x * di + bb.x;
    float v1 = acc.y * di + bb.y;
    float2 o;
    o.x = v0 > 0.f ? v0 : 0.f;
    o.y = v1 > 0.f ? v1 : 0.f;
    *(float2*)&z[(size_t)node * HID_DIM + 2 * lane] = o;
}

// ---------------- gemm2: h2p[i][j] = f16( dinv[i] * sum_k z[i][k] * W2[k][j] ) ----------------
#define G2_ZS 68
__global__ __launch_bounds__(256) void gemm2_kernel(const float* __restrict__ z,
                                                    const float* __restrict__ W2,
                                                    const float* __restrict__ dinv,
                                                    f16* __restrict__ h2p) {
    __shared__ float ws[HID_DIM * OUT_DIM];  // 2560 floats
    __shared__ float zT[HID_DIM * G2_ZS];    // 4352 floats
    int t = threadIdx.x;
    int nodeBase = blockIdx.x * 64;

    const float4* W4 = (const float4*)W2;
    float4* ws4 = (float4*)ws;
    for (int i = t; i < (HID_DIM * OUT_DIM) / 4; i += 256) ws4[i] = W4[i];

    int kg = t & 31;
    int nd = t >> 5;
#pragma unroll
    for (int m = 0; m < 8; ++m) {
        int node = nd + 8 * m;
        int n = nodeBase + node;
        float v0 = 0.f, v1 = 0.f;
        if (n < N_NODES) {
            const float* zr = z + (size_t)n * HID_DIM;
            v0 = zr[kg];
            v1 = zr[kg + 32];
        }
        zT[kg * G2_ZS + node] = v0;
        zT[(kg + 32) * G2_ZS + node] = v1;
    }
    __syncthreads();

    int g = t >> 4;   // node group of 4
    int c = t & 15;   // col group of 4; active c<10
    if (c < 10) {
        float acc[4][4] = {};
#pragma unroll 4
        for (int k = 0; k < HID_DIM; ++k) {
            float4 zv = *(const float4*)&zT[k * G2_ZS + 4 * g];
            float4 wv = *(const float4*)&ws[k * OUT_DIM + 4 * c];
            acc[0][0] += zv.x * wv.x; acc[0][1] += zv.x * wv.y; acc[0][2] += zv.x * wv.z; acc[0][3] += zv.x * wv.w;
            acc[1][0] += zv.y * wv.x; acc[1][1] += zv.y * wv.y; acc[1][2] += zv.y * wv.z; acc[1][3] += zv.y * wv.w;
            acc[2][0] += zv.z * wv.x; acc[2][1] += zv.z * wv.y; acc[2][2] += zv.z * wv.z; acc[2][3] += zv.z * wv.w;
            acc[3][0] += zv.w * wv.x; acc[3][1] += zv.w * wv.y; acc[3][2] += zv.w * wv.z; acc[3][3] += zv.w * wv.w;
        }
#pragma unroll
        for (int i = 0; i < 4; ++i) {
            int n = nodeBase + 4 * g + i;
            if (n < N_NODES) {
                float di = dinv[n];
                f16x4 o;
                o.x = (f16)(acc[i][0] * di);
                o.y = (f16)(acc[i][1] * di);
                o.z = (f16)(acc[i][2] * di);
                o.w = (f16)(acc[i][3] * di);
                *(f16x4*)&h2p[(size_t)n * OUT_DIM + 4 * c] = o;
            }
        }
    }
}

// agg2: 2 nodes per wave (32-lane halves), lanes 0..19 gather f16x2; unroll 4 + prefetch
__global__ __launch_bounds__(256) void agg2_kernel(const f16* __restrict__ h2p,
                                                   const int* __restrict__ csr,
                                                   const int* __restrict__ row_start,
                                                   const int* __restrict__ cnt,
                                                   const float* __restrict__ dinv,
                                                   const float* __restrict__ b2,
                                                   float* __restrict__ out) {
    int node = blockIdx.x * 8 + (threadIdx.x >> 5);
    int lane = threadIdx.x & 31;          // f16x2 slot: dims 2*lane, 2*lane+1 (active <20)
    if (node >= N_NODES || lane >= 20) return;
    const f16x2* h = (const f16x2*)h2p;   // row stride 20 (f16x2 units)
    float2 acc;
    {
        f16x2 sv = h[(size_t)node * 20 + lane];   // self loop
        acc.x = (float)sv.x;
        acc.y = (float)sv.y;
    }
    int n = cnt[node];
    const int* cp = csr + row_start[node];
    int k = 0;
    if (n >= 4) {
        int i0 = cp[0], i1 = cp[1], i2 = cp[2], i3 = cp[3];
        for (; k + 8 <= n; k += 4) {
            int j0 = cp[k + 4], j1 = cp[k + 5], j2 = cp[k + 6], j3 = cp[k + 7];
            f16x2 f0 = h[(size_t)i0 * 20 + lane];
            f16x2 f1 = h[(size_t)i1 * 20 + lane];
            f16x2 f2 = h[(size_t)i2 * 20 + lane];
            f16x2 f3 = h[(size_t)i3 * 20 + lane];
            acc.x += (float)f0.x + (float)f1.x + (float)f2.x + (float)f3.x;
            acc.y += (float)f0.y + (float)f1.y + (float)f2.y + (float)f3.y;
            i0 = j0; i1 = j1; i2 = j2; i3 = j3;
        }
        {
            f16x2 f0 = h[(size_t)i0 * 20 + lane];
            f16x2 f1 = h[(size_t)i1 * 20 + lane];
            f16x2 f2 = h[(size_t)i2 * 20 + lane];
            f16x2 f3 = h[(size_t)i3 * 20 + lane];
            acc.x += (float)f0.x + (float)f1.x + (float)f2.x + (float)f3.x;
            acc.y += (float)f0.y + (float)f1.y + (float)f2.y + (float)f3.y;
            k += 4;
        }
    }
    for (; k < n; ++k) {
        f16x2 f = h[(size_t)cp[k] * 20 + lane];
        acc.x += (float)f.x;
        acc.y += (float)f.y;
    }
    float di = dinv[node];
    float2 bb = *(const float2*)&b2[2 * lane];
    float2 o;
    o.x = acc.x * di + bb.x;
    o.y = acc.y * di + bb.y;
    *(float2*)&out[(size_t)node * OUT_DIM + 2 * lane] = o;
}

extern "C" void kernel_launch(void* const* d_in, const int* in_sizes, int n_in,
                              void* d_out, int out_size, void* d_ws, size_t ws_size,
                              hipStream_t stream) {
    const float* x  = (const float*)d_in[0];
    const int*   ei = (const int*)d_in[1];      // [2, E] int32
    const float* W1 = (const float*)d_in[2];
    const float* b1 = (const float*)d_in[3];
    const float* W2 = (const float*)d_in[4];
    const float* b2 = (const float*)d_in[5];
    float* out = (float*)d_out;

    const int* src = ei;
    const int* dst = ei + N_EDGES;

    int* wsi        = (int*)d_ws;
    int* hist       = wsi;
    int* base       = hist + N_CHUNKS * N_BUCKETS;
    int* bucketTotal= base + N_BUCKETS * N_CHUNKS;
    int* bucketBase = bucketTotal + 1024;
    int* row_start  = bucketBase + 1024;
    int* cnt        = row_start + NPAD;
    int* csr        = cnt + NPAD;
    int* stage      = csr + N_EDGES;
    float* dinv     = (float*)(stage + N_EDGES);
    float* z        = dinv + NPAD;
    f16*   h1p      = (f16*)(z + (size_t)N_NODES * HID_DIM);
    f16*   h2p      = h1p + (size_t)N_NODES * HID_DIM;
    f16*   w1f      = h2p + (size_t)N_NODES * OUT_DIM;   // 8192 f16 fragment-ordered W1

    hist_kernel<<<N_CHUNKS, 256, 0, stream>>>(dst, hist);
    scan_chunks_kernel<<<N_BUCKETS, 256, 0, stream>>>(hist, base, bucketTotal);
    scan_buckets_kernel<<<1, 256, 0, stream>>>(bucketTotal, bucketBase);
    scatter_kernel<<<N_CHUNKS, 256, 0, stream>>>(src, dst, base, bucketBase, stage);
    place_kernel<<<N_BUCKETS, 256, 0, stream>>>(stage, bucketBase, csr, row_start, cnt, dinv);

    w1frag_kernel<<<4, 256, 0, stream>>>(W1, w1f);
    gemm1_kernel<<<(N_NODES + 63) / 64, 256, 0, stream>>>(x, w1f, dinv, h1p);
    agg1_kernel<<<(N_NODES + 7) / 8, 256, 0, stream>>>(h1p, csr, row_start, cnt, dinv, b1, z);
    gemm2_kernel<<<(N_NODES + 63) / 64, 256, 0, stream>>>(z, W2, dinv, h2p);
    agg2_kernel<<<(N_NODES + 7) / 8, 256, 0, stream>>>(h2p, csr, row_start, cnt, dinv, b2, out);
}

// Round 10
// 226.490 us; speedup vs baseline: 3.2355x; 1.0578x over previous
//
#include <hip/hip_runtime.h>
#include <math.h>

#define N_NODES 100000
#define N_EDGES 1600000
#define IN_DIM 128
#define HID_DIM 64
#define OUT_DIM 40

#define NPAD 102400

#define BUCKET_SHIFT 7
#define BUCKET_NODES 128
#define N_BUCKETS 782          // ceil(100000/128)
#define CHUNK 2048
#define N_CHUNKS 784           // 8 XCD groups x 98; 784*2048 >= N_EDGES

typedef _Float16 f16;
typedef _Float16 f16x2 __attribute__((ext_vector_type(2)));
typedef _Float16 f16x4 __attribute__((ext_vector_type(4)));
typedef _Float16 f16x8 __attribute__((ext_vector_type(8)));
typedef float f32x4 __attribute__((ext_vector_type(4)));

// -------- workspace layout --------
// ints:  hist[N_CHUNKS*N_BUCKETS] | base[N_BUCKETS*N_CHUNKS] | bucketTotal[1024] |
//        bucketBase[1024] | row_start[NPAD] | cnt[NPAD] | csr[E] | stage[E]
// floats: dinv[NPAD]
// f16:    h1p[N*64] | h2p[N*40] | w1f[8192] | w2f[3072]
// NO memset needed: every buffer fully written before read each launch.

// 1) per-chunk LDS histogram over dst buckets; coalesced row write
__global__ __launch_bounds__(256) void hist_kernel(const int* __restrict__ dst,
                                                   int* __restrict__ hist) {
    __shared__ int lh[N_BUCKETS];
    int c = blockIdx.x;
    int t = threadIdx.x;
    for (int b = t; b < N_BUCKETS; b += 256) lh[b] = 0;
    __syncthreads();
    int e0 = c * CHUNK;
    for (int i = t; i < CHUNK; i += 256) {
        int e = e0 + i;
        if (e < N_EDGES) atomicAdd(&lh[dst[e] >> BUCKET_SHIFT], 1);
    }
    __syncthreads();
    for (int b = t; b < N_BUCKETS; b += 256) hist[c * N_BUCKETS + b] = lh[b];
}

// 2) per-bucket exclusive scan over chunks -> base[b][c], bucketTotal[b]
__global__ __launch_bounds__(256) void scan_chunks_kernel(const int* __restrict__ hist,
                                                          int* __restrict__ base,
                                                          int* __restrict__ bucketTotal) {
    __shared__ int lds[256];
    int b = blockIdx.x;
    int t = threadIdx.x;
    int v[4];
    int s = 0;
    for (int k = 0; k < 4; ++k) {
        int c = 4 * t + k;
        int cv = (c < N_CHUNKS) ? hist[c * N_BUCKETS + b] : 0;
        v[k] = s;
        s += cv;
    }
    lds[t] = s;
    __syncthreads();
    for (int off = 1; off < 256; off <<= 1) {
        int val = (t >= off) ? lds[t - off] : 0;
        __syncthreads();
        lds[t] += val;
        __syncthreads();
    }
    int excl = (t == 0) ? 0 : lds[t - 1];
    for (int k = 0; k < 4; ++k) {
        int c = 4 * t + k;
        if (c < N_CHUNKS) base[b * N_CHUNKS + c] = excl + v[k];
    }
    if (t == 255) bucketTotal[b] = lds[255];
}

// 3) exclusive scan over 782 bucket totals -> bucketBase
__global__ __launch_bounds__(256) void scan_buckets_kernel(const int* __restrict__ bucketTotal,
                                                           int* __restrict__ bucketBase) {
    __shared__ int lds[256];
    int t = threadIdx.x;
    int v[4];
    int s = 0;
    for (int k = 0; k < 4; ++k) {
        int b = 4 * t + k;
        int cv = (b < N_BUCKETS) ? bucketTotal[b] : 0;
        v[k] = s;
        s += cv;
    }
    lds[t] = s;
    __syncthreads();
    for (int off = 1; off < 256; off <<= 1) {
        int val = (t >= off) ? lds[t - off] : 0;
        __syncthreads();
        lds[t] += val;
        __syncthreads();
    }
    int excl = (t == 0) ? 0 : lds[t - 1];
    for (int k = 0; k < 4; ++k) {
        int b = 4 * t + k;
        if (b < N_BUCKETS) bucketBase[b] = excl + v[k];
    }
}

// 4) deterministic scatter into bucket-grouped stage; LDS slice counters only.
__global__ __launch_bounds__(256) void scatter_kernel(const int* __restrict__ src,
                                                      const int* __restrict__ dst,
                                                      const int* __restrict__ base,
                                                      const int* __restrict__ bucketBase,
                                                      int* __restrict__ stage) {
    __shared__ int lbase[N_BUCKETS];
    __shared__ int lcnt[N_BUCKETS];
    int bid = blockIdx.x;
    int chunk = (bid & 7) * 98 + (bid >> 3);   // bijection on [0,784)
    int t = threadIdx.x;
    for (int b = t; b < N_BUCKETS; b += 256) {
        lbase[b] = base[b * N_CHUNKS + chunk] + bucketBase[b];
        lcnt[b] = 0;
    }
    __syncthreads();
    int e0 = chunk * CHUNK;
    for (int i = t; i < CHUNK; i += 256) {
        int e = e0 + i;
        if (e < N_EDGES) {
            int d = dst[e];
            int b = d >> BUCKET_SHIFT;
            int pos = lbase[b] + atomicAdd(&lcnt[b], 1);
            stage[pos] = ((d & (BUCKET_NODES - 1)) << 17) | src[e];
        }
    }
}

// 5) one block per bucket: LDS node histogram + scan -> row_start/cnt/dinv + csr place
__global__ __launch_bounds__(256) void place_kernel(const int* __restrict__ stage,
                                                    const int* __restrict__ bucketBase,
                                                    int* __restrict__ csr,
                                                    int* __restrict__ row_start,
                                                    int* __restrict__ cnt,
                                                    float* __restrict__ dinv) {
    __shared__ int lhist[BUCKET_NODES];
    __shared__ int lscan[BUCKET_NODES];
    __shared__ int lstart[BUCKET_NODES];
    __shared__ int lcur[BUCKET_NODES];
    int b = blockIdx.x;
    int t = threadIdx.x;
    int est = bucketBase[b];
    int een = (b == N_BUCKETS - 1) ? N_EDGES : bucketBase[b + 1];
    if (t < BUCKET_NODES) { lhist[t] = 0; lcur[t] = 0; }
    __syncthreads();
    for (int e = est + t; e < een; e += 256) atomicAdd(&lhist[stage[e] >> 17], 1);
    __syncthreads();
    if (t < BUCKET_NODES) lscan[t] = lhist[t];
    __syncthreads();
    for (int off = 1; off < BUCKET_NODES; off <<= 1) {
        int val = (t >= off && t < BUCKET_NODES) ? lscan[t - off] : 0;
        __syncthreads();
        if (t < BUCKET_NODES) lscan[t] += val;
        __syncthreads();
    }
    if (t < BUCKET_NODES) {
        int myexcl = (t == 0) ? 0 : lscan[t - 1];
        lstart[t] = est + myexcl;
        int node = (b << BUCKET_SHIFT) + t;
        if (node < N_NODES) {
            row_start[node] = est + myexcl;
            cnt[node] = lhist[t];
            dinv[node] = rsqrtf((float)lhist[t] + 1.0f);
        }
    }
    __syncthreads();
    for (int e = est + t; e < een; e += 256) {
        int rec = stage[e];
        int dl = rec >> 17;
        int pos = lstart[dl] + atomicAdd(&lcur[dl], 1);
        csr[pos] = rec & 0x1FFFF;
    }
}

// ---- W1,W2 -> fragment-ordered f16 (B-operand layout for mfma_f32_16x16x32_f16) ----
// W1: 16 frags f=s*4+c (s=0..3 k-steps, c=0..3 col-tiles), lane L holds
//     B[32s+(L>>4)*8+j][16c+(L&15)] as f16x8 at w1f8[f*64+L].
// W2: 6 frags f=s*3+c (s=0..1, c=0..2, cols 40..47 zero-padded).
__global__ __launch_bounds__(256) void wfrag_kernel(const float* __restrict__ W1,
                                                    const float* __restrict__ W2,
                                                    f16* __restrict__ w1f,
                                                    f16* __restrict__ w2f) {
    int g = blockIdx.x * 256 + threadIdx.x;
    if (g < 1024) {
        int f = g >> 6, L = g & 63;
        int s = f >> 2, c = f & 3;
        int q = L >> 4, n = L & 15;
        f16x8 v;
#pragma unroll
        for (int j = 0; j < 8; ++j) v[j] = (f16)W1[(32 * s + 8 * q + j) * HID_DIM + 16 * c + n];
        *(f16x8*)&w1f[(size_t)g * 8] = v;
    } else if (g < 1024 + 384) {
        int gg = g - 1024;
        int f = gg >> 6, L = gg & 63;
        int s = f / 3, c = f % 3;
        int q = L >> 4, n = L & 15;
        int col = 16 * c + n;
        f16x8 v;
#pragma unroll
        for (int j = 0; j < 8; ++j)
            v[j] = (col < OUT_DIM) ? (f16)W2[(32 * s + 8 * q + j) * OUT_DIM + col] : (f16)0.f;
        *(f16x8*)&w2f[(size_t)gg * 8] = v;
    }
}

// ---------------- gemm1 (MFMA): h1p = f16( dinv * (x @ W1) ) ----------------
__global__ __launch_bounds__(256) void gemm1_kernel(const float* __restrict__ x,
                                                    const f16* __restrict__ w1f,
                                                    const float* __restrict__ dinv,
                                                    f16* __restrict__ h1p) {
    __shared__ f16 aT[1088 * 8];   // 17408 B
    int t = threadIdx.x;
    int nodeBase = blockIdx.x * 64;
    int L = t & 63;

    const f16x8* w1f8 = (const f16x8*)w1f;
    f16x8 bfrag[16];
#pragma unroll
    for (int f = 0; f < 16; ++f) bfrag[f] = w1f8[f * 64 + L];

#pragma unroll
    for (int i = 0; i < 8; ++i) {
        int idx = i * 256 + t;
        int node = idx >> 5;
        int col4 = idx & 31;
        int gnode = nodeBase + node;
        if (gnode >= N_NODES) gnode = N_NODES - 1;
        float4 v = *(const float4*)&x[(size_t)gnode * IN_DIM + col4 * 4];
        int w = node >> 4, m = node & 15;
        int s = col4 >> 3, q = (col4 >> 1) & 3, j0 = (col4 & 1) * 4;
        f16x4 h;
        h.x = (f16)v.x; h.y = (f16)v.y; h.z = (f16)v.z; h.w = (f16)v.w;
        int idx16 = (w * 4 + s) * 68 + 17 * q + m;
        *(f16x4*)&aT[idx16 * 8 + j0] = h;
    }
    __syncthreads();

    int wv = t >> 6;
    int q = L >> 4, m = L & 15;
    f32x4 acc[4] = {};
#pragma unroll
    for (int s = 0; s < 4; ++s) {
        f16x8 afrag = *(const f16x8*)&aT[((wv * 4 + s) * 68 + 17 * q + m) * 8];
#pragma unroll
        for (int c = 0; c < 4; ++c)
            acc[c] = __builtin_amdgcn_mfma_f32_16x16x32_f16(afrag, bfrag[s * 4 + c], acc[c], 0, 0, 0);
    }

#pragma unroll
    for (int r = 0; r < 4; ++r) {
        int node = nodeBase + 16 * wv + q * 4 + r;
        if (node < N_NODES) {
            float di = dinv[node];
#pragma unroll
            for (int c = 0; c < 4; ++c)
                h1p[(size_t)node * HID_DIM + 16 * c + m] = (f16)(acc[c][r] * di);
        }
    }
}

// ---------------- fused agg1 + gemm2 ----------------
// Block = 64 nodes. Phase 1: gather-sum fp16 h1p rows (2 nodes per wave per iter,
// 8 iters), fuse self-loop+dinv+bias+relu, store z tile to LDS as f16 (stride 72
// -> 16B-aligned b128 A-frag reads, <=2-way write conflicts). Phase 2: MFMA
// z @ W2 (cols zero-padded to 48), epilogue *dinv -> h2p.
#define ZSTR 72
__global__ __launch_bounds__(256) void agg1mm_kernel(const f16* __restrict__ h1p,
                                                     const int* __restrict__ csr,
                                                     const int* __restrict__ row_start,
                                                     const int* __restrict__ cnt,
                                                     const float* __restrict__ dinv,
                                                     const float* __restrict__ b1,
                                                     const f16* __restrict__ w2f,
                                                     f16* __restrict__ h2p) {
    __shared__ f16 zT[64 * ZSTR];   // 9216 B
    int t = threadIdx.x;
    int nodeBase = blockIdx.x * 64;
    int halfw = t >> 5;             // 0..7
    int lane = t & 31;              // f16x2 slot: dims 2*lane, 2*lane+1
    const f16x2* h = (const f16x2*)h1p;   // row stride 32 f16x2
    float2 bb = *(const float2*)&b1[2 * lane];

    for (int r = 0; r < 8; ++r) {
        int nodeLocal = r * 8 + halfw;
        int node = nodeBase + nodeLocal;
        float2 acc;
        acc.x = 0.f; acc.y = 0.f;
        if (node < N_NODES) {
            f16x2 sv = h[(size_t)node * 32 + lane];   // self loop
            acc.x = (float)sv.x;
            acc.y = (float)sv.y;
            int n = cnt[node];
            const int* cp = csr + row_start[node];
            int k = 0;
            if (n >= 4) {
                int i0 = cp[0], i1 = cp[1], i2 = cp[2], i3 = cp[3];
                for (; k + 8 <= n; k += 4) {
                    int j0 = cp[k + 4], j1 = cp[k + 5], j2 = cp[k + 6], j3 = cp[k + 7];
                    f16x2 f0 = h[(size_t)i0 * 32 + lane];
                    f16x2 f1 = h[(size_t)i1 * 32 + lane];
                    f16x2 f2 = h[(size_t)i2 * 32 + lane];
                    f16x2 f3 = h[(size_t)i3 * 32 + lane];
                    acc.x += (float)f0.x + (float)f1.x + (float)f2.x + (float)f3.x;
                    acc.y += (float)f0.y + (float)f1.y + (float)f2.y + (float)f3.y;
                    i0 = j0; i1 = j1; i2 = j2; i3 = j3;
                }
                {
                    f16x2 f0 = h[(size_t)i0 * 32 + lane];
                    f16x2 f1 = h[(size_t)i1 * 32 + lane];
                    f16x2 f2 = h[(size_t)i2 * 32 + lane];
                    f16x2 f3 = h[(size_t)i3 * 32 + lane];
                    acc.x += (float)f0.x + (float)f1.x + (float)f2.x + (float)f3.x;
                    acc.y += (float)f0.y + (float)f1.y + (float)f2.y + (float)f3.y;
                    k += 4;
                }
            }
            for (; k < n; ++k) {
                f16x2 f = h[(size_t)cp[k] * 32 + lane];
                acc.x += (float)f.x;
                acc.y += (float)f.y;
            }
            float di = dinv[node];
            float v0 = acc.x * di + bb.x;
            float v1 = acc.y * di + bb.y;
            acc.x = v0 > 0.f ? v0 : 0.f;
            acc.y = v1 > 0.f ? v1 : 0.f;
        }
        f16x2 o;
        o.x = (f16)acc.x;
        o.y = (f16)acc.y;
        *(f16x2*)&zT[nodeLocal * ZSTR + 2 * lane] = o;
    }
    __syncthreads();

    // Phase 2: wave wv -> m-tile wv (nodes nodeBase+16*wv .. +15)
    int wv = t >> 6;
    int L = t & 63;
    int q = L >> 4, m = L & 15;
    const f16x8* w2f8 = (const f16x8*)w2f;
    f32x4 acc2[3] = {};
#pragma unroll
    for (int s = 0; s < 2; ++s) {
        f16x8 afrag = *(const f16x8*)&zT[(16 * wv + m) * ZSTR + 32 * s + 8 * q];
#pragma unroll
        for (int c = 0; c < 3; ++c)
            acc2[c] = __builtin_amdgcn_mfma_f32_16x16x32_f16(afrag, w2f8[(s * 3 + c) * 64 + L], acc2[c], 0, 0, 0);
    }
#pragma unroll
    for (int r = 0; r < 4; ++r) {
        int node = nodeBase + 16 * wv + q * 4 + r;
        if (node < N_NODES) {
            float di = dinv[node];
            h2p[(size_t)node * OUT_DIM + m]      = (f16)(acc2[0][r] * di);
            h2p[(size_t)node * OUT_DIM + 16 + m] = (f16)(acc2[1][r] * di);
            if (m < 8)
                h2p[(size_t)node * OUT_DIM + 32 + m] = (f16)(acc2[2][r] * di);
        }
    }
}

// agg2: 2 nodes per wave (32-lane halves), lanes 0..19 gather f16x2; unroll 4 + prefetch
__global__ __launch_bounds__(256) void agg2_kernel(const f16* __restrict__ h2p,
                                                   const int* __restrict__ csr,
                                                   const int* __restrict__ row_start,
                                                   const int* __restrict__ cnt,
                                                   const float* __restrict__ dinv,
                                                   const float* __restrict__ b2,
                                                   float* __restrict__ out) {
    int node = blockIdx.x * 8 + (threadIdx.x >> 5);
    int lane = threadIdx.x & 31;          // f16x2 slot: dims 2*lane, 2*lane+1 (active <20)
    if (node >= N_NODES || lane >= 20) return;
    const f16x2* h = (const f16x2*)h2p;   // row stride 20 (f16x2 units)
    float2 acc;
    {
        f16x2 sv = h[(size_t)node * 20 + lane];   // self loop
        acc.x = (float)sv.x;
        acc.y = (float)sv.y;
    }
    int n = cnt[node];
    const int* cp = csr + row_start[node];
    int k = 0;
    if (n >= 4) {
        int i0 = cp[0], i1 = cp[1], i2 = cp[2], i3 = cp[3];
        for (; k + 8 <= n; k += 4) {
            int j0 = cp[k + 4], j1 = cp[k + 5], j2 = cp[k + 6], j3 = cp[k + 7];
            f16x2 f0 = h[(size_t)i0 * 20 + lane];
            f16x2 f1 = h[(size_t)i1 * 20 + lane];
            f16x2 f2 = h[(size_t)i2 * 20 + lane];
            f16x2 f3 = h[(size_t)i3 * 20 + lane];
            acc.x += (float)f0.x + (float)f1.x + (float)f2.x + (float)f3.x;
            acc.y += (float)f0.y + (float)f1.y + (float)f2.y + (float)f3.y;
            i0 = j0; i1 = j1; i2 = j2; i3 = j3;
        }
        {
            f16x2 f0 = h[(size_t)i0 * 20 + lane];
            f16x2 f1 = h[(size_t)i1 * 20 + lane];
            f16x2 f2 = h[(size_t)i2 * 20 + lane];
            f16x2 f3 = h[(size_t)i3 * 20 + lane];
            acc.x += (float)f0.x + (float)f1.x + (float)f2.x + (float)f3.x;
            acc.y += (float)f0.y + (float)f1.y + (float)f2.y + (float)f3.y;
            k += 4;
        }
    }
    for (; k < n; ++k) {
        f16x2 f = h[(size_t)cp[k] * 20 + lane];
        acc.x += (float)f.x;
        acc.y += (float)f.y;
    }
    float di = dinv[node];
    float2 bb = *(const float2*)&b2[2 * lane];
    float2 o;
    o.x = acc.x * di + bb.x;
    o.y = acc.y * di + bb.y;
    *(float2*)&out[(size_t)node * OUT_DIM + 2 * lane] = o;
}

extern "C" void kernel_launch(void* const* d_in, const int* in_sizes, int n_in,
                              void* d_out, int out_size, void* d_ws, size_t ws_size,
                              hipStream_t stream) {
    const float* x  = (const float*)d_in[0];
    const int*   ei = (const int*)d_in[1];      // [2, E] int32
    const float* W1 = (const float*)d_in[2];
    const float* b1 = (const float*)d_in[3];
    const float* W2 = (const float*)d_in[4];
    const float* b2 = (const float*)d_in[5];
    float* out = (float*)d_out;

    const int* src = ei;
    const int* dst = ei + N_EDGES;

    int* wsi        = (int*)d_ws;
    int* hist       = wsi;
    int* base       = hist + N_CHUNKS * N_BUCKETS;
    int* bucketTotal= base + N_BUCKETS * N_CHUNKS;
    int* bucketBase = bucketTotal + 1024;
    int* row_start  = bucketBase + 1024;
    int* cnt        = row_start + NPAD;
    int* csr        = cnt + NPAD;
    int* stage      = csr + N_EDGES;
    float* dinv     = (float*)(stage + N_EDGES);
    f16*   h1p      = (f16*)(dinv + NPAD);
    f16*   h2p      = h1p + (size_t)N_NODES * HID_DIM;
    f16*   w1f      = h2p + (size_t)N_NODES * OUT_DIM;   // 8192 f16
    f16*   w2f      = w1f + 8192;                        // 3072 f16

    hist_kernel<<<N_CHUNKS, 256, 0, stream>>>(dst, hist);
    scan_chunks_kernel<<<N_BUCKETS, 256, 0, stream>>>(hist, base, bucketTotal);
    scan_buckets_kernel<<<1, 256, 0, stream>>>(bucketTotal, bucketBase);
    scatter_kernel<<<N_CHUNKS, 256, 0, stream>>>(src, dst, base, bucketBase, stage);
    place_kernel<<<N_BUCKETS, 256, 0, stream>>>(stage, bucketBase, csr, row_start, cnt, dinv);

    wfrag_kernel<<<6, 256, 0, stream>>>(W1, W2, w1f, w2f);
    gemm1_kernel<<<(N_NODES + 63) / 64, 256, 0, stream>>>(x, w1f, dinv, h1p);
    agg1mm_kernel<<<(N_NODES + 63) / 64, 256, 0, stream>>>(h1p, csr, row_start, cnt, dinv, b1, w2f, h2p);
    agg2_kernel<<<(N_NODES + 7) / 8, 256, 0, stream>>>(h2p, csr, row_start, cnt, dinv, b2, out);
}